// Round 21
// baseline (787.810 us; speedup 1.0000x reference)
//
#include <hip/hip_runtime.h>
#include <math.h>

#define H 64
#define VOCABN 64
#define LSEQ 2048
#define LN_EPS 1e-5f
#define TCH 8
#define NCHUNK (LSEQ / TCH)   // 256

// ---------- generic DPP add helper ----------
template <int CTRL>
__device__ __forceinline__ float dpp_add(float x) {
  return x + __int_as_float(__builtin_amdgcn_update_dpp(
      0, __float_as_int(x), CTRL, 0xF, 0xF, true));
}

// all-lane sum with broadcast result (tables / readout only)
__device__ __forceinline__ float wave_allsum(float x) {
  x = dpp_add<0xB1>(x);   // quad_perm [1,0,3,2]
  x = dpp_add<0x4E>(x);   // quad_perm [2,3,0,1]
  x = dpp_add<0x141>(x);  // row_half_mirror
  x = dpp_add<0x140>(x);  // row_mirror
  x += __shfl_xor(x, 16, 64);
  x += __shfl_xor(x, 32, 64);
  return x;
}

// all-VALU wave64 reduction: lane 63 holds the total (rounds 3/7-20 validated)
__device__ __forceinline__ float reduce_to_lane63(float x) {
  x = dpp_add<0x111>(x);  // row_shr:1
  x = dpp_add<0x112>(x);  // row_shr:2
  x = dpp_add<0x114>(x);  // row_shr:4
  x = dpp_add<0x118>(x);  // row_shr:8
  x = dpp_add<0x142>(x);  // row_bcast:15
  x = dpp_add<0x143>(x);  // row_bcast:31
  return x;
}

__device__ __forceinline__ float rdlf(float v, int lane) {
  return __int_as_float(__builtin_amdgcn_readlane(__float_as_int(v), lane));
}

// ---------------- Kernel A: per-token tables (verbatim rounds 7-20, passed) ----------------
__global__ __launch_bounds__(64) void tables_kernel(
    const float* __restrict__ embed, const float* __restrict__ W1, const float* __restrict__ b1,
    const float* __restrict__ W2, const float* __restrict__ b2,
    const float* __restrict__ ln_g, const float* __restrict__ ln_b,
    const float* __restrict__ Wk, const float* __restrict__ Wv,
    float* __restrict__ Htab, float* __restrict__ Ktab, float* __restrict__ Vtab,
    float* __restrict__ nvtab)
{
  __shared__ float hs[H];
  __shared__ float ff1[2 * H];
  __shared__ float lns[H];
  const int c = blockIdx.x;
  const int i = threadIdx.x;

  float e = embed[c * H + i];
  hs[i] = e;
  __syncthreads();

  float r1 = b1[i], r2 = b1[i + H];
  for (int j = 0; j < H; ++j) {
    float hj = hs[j];
    r1 = fmaf(W1[i * H + j], hj, r1);
    r2 = fmaf(W1[(i + H) * H + j], hj, r2);
  }
  ff1[i]     = fmaxf(r1, 0.f);
  ff1[i + H] = fmaxf(r2, 0.f);
  __syncthreads();

  float o = b2[i];
  for (int m = 0; m < 2 * H; ++m) o = fmaf(W2[i * 2 * H + m], ff1[m], o);
  float y = e + o;

  float mu  = wave_allsum(y) * (1.f / H);
  float d   = y - mu;
  float var = wave_allsum(d * d) * (1.f / H);
  float ln  = d * (1.f / sqrtf(var + LN_EPS)) * ln_g[i] + ln_b[i];
  lns[i] = ln;
  __syncthreads();
  Htab[c * H + i] = ln;

  float k = 0.f, v = 0.f;
  for (int j = 0; j < H; ++j) {
    float lj = lns[j];
    k = fmaf(Wk[i * H + j], lj, k);
    v = fmaf(Wv[i * H + j], lj, v);
  }
  float nk = sqrtf(wave_allsum(k * k));
  Ktab[c * H + i] = k / fmaxf(nk, 1e-12f);
  Vtab[c * H + i] = v;
  float nv = sqrtf(wave_allsum(v * v));
  if (i == 0) nvtab[c] = 0.4f * nv;   // gate threshold, sqrt domain
}

// ---------------- Kernel B: chunked-WY scan (T=8), vector-load + readlane flush ----------------
// Same structure as round 20 (passed, bitwise-stable) with every flush BROADCAST
// b128 replaced by {stride-1 vector row load + readlane(SGPR idx)} — moves ~770
// cy/wave/chunk off the shared LDS pipe onto private VALU pipes. All G/K values,
// fmaf operands and chronological order identical to round 20 -> bitwise output.
__global__ __launch_bounds__(256, 1) void scan_kernel(
    const int* __restrict__ x, const float* __restrict__ Htab,
    const float* __restrict__ Ktab, const float* __restrict__ Vtab,
    const float* __restrict__ nvtab,
    const float* __restrict__ Wq, const float* __restrict__ Wr,
    const float* __restrict__ alpha, const float* __restrict__ Wout,
    const float* __restrict__ bout, float* __restrict__ out)
{
  __shared__ float4 Kl4[VOCABN * H / 4];   // khat [c][j]; becomes M_N after scan
  __shared__ float  Gl[VOCABN * H];        // Gram [c][cc]; becomes M_T after scan
  __shared__ float4 Rl4[VOCABN * H / 4];   // residual [c][i]
  __shared__ int    xl[LSEQ];
  __shared__ float  gin[NCHUNK * 36 + 64]; // per-chunk: 28 tri + 8 thr (padded)
  __shared__ float  thl[VOCABN];
  __shared__ float  hbuf[H];
  __shared__ float  qbuf[H];
  __shared__ float  mbuf[H];
  float* Kl = (float*)Kl4;
  float* Rl = (float*)Rl4;

  const int b    = blockIdx.x;
  const int tid  = threadIdx.x;
  const int lane = tid & 63;
  const int wid  = tid >> 6;
  const int wids = __builtin_amdgcn_readfirstlane(wid);

  // ---- stage tables + token row into LDS (256 threads) ----
  {
    const float4* Kg = (const float4*)Ktab;
    const float4* Vg = (const float4*)Vtab;
    for (int q = tid; q < VOCABN * H / 4; q += 256) { Kl4[q] = Kg[q]; Rl4[q] = Vg[q]; }
    const int4* xg = (const int4*)(x + b * LSEQ);
    int4* xl4 = (int4*)xl;
    for (int q = tid; q < LSEQ / 4; q += 256) xl4[q] = xg[q];
    if (tid < VOCABN) thl[tid] = nvtab[tid];
  }
  __syncthreads();

  // ---- Gram in LDS, 16 rows per wave (verbatim rounds 10-20) ----
  {
    float4 kr[16];
#pragma unroll
    for (int q = 0; q < 16; ++q) kr[q] = Kl4[lane * 16 + q];
    for (int r = 0; r < 16; ++r) {
      const int c2 = wid * 16 + r;
      const float4* kp2 = (const float4*)(Kl + c2 * H);
      float a0 = 0.f, a1 = 0.f, a2 = 0.f, a3 = 0.f;
#pragma unroll
      for (int q = 0; q < 16; ++q) {
        float4 kq = kp2[q];
        a0 = fmaf(kr[q].x, kq.x, a0);
        a1 = fmaf(kr[q].y, kq.y, a1);
        a2 = fmaf(kr[q].z, kq.z, a2);
        a3 = fmaf(kr[q].w, kq.w, a3);
      }
      Gl[c2 * H + lane] = (a0 + a1) + (a2 + a3);
    }
  }
  __syncthreads();

  // ---- stage per-chunk {28-entry Gram triangle + 8 thresholds} (one-time) ----
  for (int n = tid; n < NCHUNK; n += 256) {
    const int base = n * TCH;
    int ct[8];
#pragma unroll
    for (int i = 0; i < 8; ++i) ct[i] = xl[base + i];
    float* gout = gin + n * 36;
    int idx = 0;
    for (int i = 0; i < 7; ++i)
      for (int j = i + 1; j < 8; ++j)
        gout[idx++] = Gl[ct[i] * H + ct[j]];
    for (int i = 0; i < 8; ++i) gout[28 + i] = thl[ct[i]];
  }
  __syncthreads();

  // M column slice: Mw[q] holds M[lane][wids*16 + 4q .. 4q+3]
  float4 Mw[4];
#pragma unroll
  for (int q = 0; q < 4; ++q) Mw[q] = make_float4(0.f, 0.f, 0.f, 0.f);

  for (int n = 0; n < NCHUNK; ++n) {
    const int base = n * TCH;
    const int4 t0 = *(const int4*)(xl + base);
    const int4 t1 = *(const int4*)(xl + base + 4);
    int c_[8];
    c_[0] = __builtin_amdgcn_readfirstlane(t0.x);
    c_[1] = __builtin_amdgcn_readfirstlane(t0.y);
    c_[2] = __builtin_amdgcn_readfirstlane(t0.z);
    c_[3] = __builtin_amdgcn_readfirstlane(t0.w);
    c_[4] = __builtin_amdgcn_readfirstlane(t1.x);
    c_[5] = __builtin_amdgcn_readfirstlane(t1.y);
    c_[6] = __builtin_amdgcn_readfirstlane(t1.z);
    c_[7] = __builtin_amdgcn_readfirstlane(t1.w);

    // stride-1 vector loads: residual rows + G rows + K rows + packed coef word
    float rr[8], gv[8], kv[8];
#pragma unroll
    for (int i = 0; i < 8; ++i) rr[i] = Rl[c_[i] * H + lane];
#pragma unroll
    for (int i = 0; i < 8; ++i) gv[i] = Gl[c_[i] * H + lane];
#pragma unroll
    for (int i = 0; i < 8; ++i) kv[i] = Kl[c_[i] * H + lane];
    const float gvn = gin[n * 36 + lane];   // lanes 0..35 valid (padded)

    // thresholds as uniform scalars (same staged bits as r20)
    float tt[8];
#pragma unroll
    for (int i = 0; i < 8; ++i) tt[i] = rdlf(gvn, 28 + i);

    // ---- 8 register-only gates (chronological; bitwise == r20) ----
    float dd[8];
#pragma unroll
    for (int i = 0; i < 8; ++i) {
      float nd2 = reduce_to_lane63(rr[i] * rr[i]);
      float nds = sqrtf(rdlf(nd2, 63));
      dd[i] = 0.f;
      if (nds > tt[i]) {                   // block-uniform (scalar compare)
        dd[i] = rr[i];
#pragma unroll
        for (int j = i + 1; j < 8; ++j)
          rr[j] = fmaf(-rdlf(gvn, i * (15 - i) / 2 + (j - i - 1)), dd[i], rr[j]);
      }
    }

    // ---- flush: one barrier pair per chunk ----
    __syncthreads();                       // read-fence
    // R RMW: 16 rows/wave; coefficients via readlane from gv rows (SGPR index)
#pragma unroll
    for (int r = 0; r < 16; ++r) {
      const int cc = wids * 16 + r;
      float val = Rl[cc * H + lane];
#pragma unroll
      for (int i = 0; i < 8; ++i)
        val = fmaf(-rdlf(gv[i], cc), dd[i], val);   // d=0 slots: exact no-ops
      Rl[cc * H + lane] = val;
    }
    // M column slices: chronological d_0..d_7 per component (== r20 order)
#pragma unroll
    for (int q = 0; q < 4; ++q) {
      const int jb = wids * 16 + q * 4;
#pragma unroll
      for (int i = 0; i < 8; ++i) {
        Mw[q].x = fmaf(dd[i], rdlf(kv[i], jb + 0), Mw[q].x);
        Mw[q].y = fmaf(dd[i], rdlf(kv[i], jb + 1), Mw[q].y);
        Mw[q].z = fmaf(dd[i], rdlf(kv[i], jb + 2), Mw[q].z);
        Mw[q].w = fmaf(dd[i], rdlf(kv[i], jb + 3), Mw[q].w);
      }
    }
    __syncthreads();                       // write-fence
  }

  // ---- reassemble M: Gl -> M_T (stride H), Kl -> M_N (rounds 12-20 layout) ----
  __syncthreads();
  float* Mt = Gl;                          // Gram dead after scan
#pragma unroll
  for (int r = 0; r < 4; ++r) {
    const int jb = wids * 16 + r * 4;
    float4 m = Mw[r];
    Mt[(jb + 0) * H + lane] = m.x;
    Mt[(jb + 1) * H + lane] = m.y;
    Mt[(jb + 2) * H + lane] = m.z;
    Mt[(jb + 3) * H + lane] = m.w;
    Kl[lane * H + jb + 0] = m.x;
    Kl[lane * H + jb + 1] = m.y;
    Kl[lane * H + jb + 2] = m.z;
    Kl[lane * H + jb + 3] = m.w;
  }
  __syncthreads();

  // ---------------- fused readout: wave 0 (verbatim rounds 12-20, passed) ----------------
  if (wid == 0) {
    const int clast = xl[LSEQ - 1];
    hbuf[lane] = Htab[clast * H + lane];

    float qi = 0.f;
    for (int j = 0; j < H; ++j) qi = fmaf(Wq[lane * H + j], hbuf[j], qi);
    qbuf[lane] = qi;

    float qri = 0.f;
    for (int j = 0; j < H; ++j) qri = fmaf(Wr[lane * H + j], qbuf[j], qri);

    // slot norms^2: lane s reads M_N column s (conflict-free)
    float n2r = 0.f;
    for (int i2 = 0; i2 < H; ++i2) { float m = Kl[i2 * H + lane]; n2r = fmaf(m, m, n2r); }

    // top-8 slots by norm (ties -> smaller index)
    const int KS = 8;
    int idxs[KS];
    float nloc = n2r;
#pragma unroll
    for (int k = 0; k < KS; ++k) {
      float v = nloc; int idx = lane;
#pragma unroll
      for (int s = 1; s < 64; s <<= 1) {
        float ov = __shfl_xor(v, s, 64);
        int   oi = __shfl_xor(idx, s, 64);
        if (ov > v || (ov == v && oi < idx)) { v = ov; idx = oi; }
      }
      idxs[k] = idx;
      if (lane == idx) nloc = -1.f;
    }

    float sel[KS], lg[KS];
#pragma unroll
    for (int k = 0; k < KS; ++k) {
      float s = Mt[idxs[k] * H + lane];     // M_T[idx][lane]
      sel[k] = s;
      lg[k] = wave_allsum(s * qri) * 0.125f;   // / sqrt(64)
    }
    float lmax = lg[0];
#pragma unroll
    for (int k = 1; k < KS; ++k) lmax = fmaxf(lmax, lg[k]);
    float esum = 0.f, retro = 0.f;
#pragma unroll
    for (int k = 0; k < KS; ++k) {
      float e = expf(lg[k] - lmax);
      esum += e;
      retro = fmaf(e, sel[k], retro);
    }
    retro /= esum;

    // m_ctx = M q : lane i, ascending j reading M_T[j][lane] (conflict-free)
    float mc = 0.f;
    for (int j = 0; j < H; ++j) mc = fmaf(Mt[j * H + lane], qbuf[j], mc);

    float a = 1.f / (1.f + expf(-alpha[0]));
    float mixed = fmaxf(fmaf(a, retro, (1.f - a) * mc), 0.f);
    mbuf[lane] = mixed;

    float oo = bout[lane];
    for (int i2 = 0; i2 < H; ++i2) oo = fmaf(Wout[lane * H + i2], mbuf[i2], oo);
    out[b * VOCABN + lane] = oo;
  }
}

extern "C" void kernel_launch(void* const* d_in, const int* in_sizes, int n_in,
                              void* d_out, int out_size, void* d_ws, size_t ws_size,
                              hipStream_t stream) {
  const int*   x     = (const int*)d_in[0];
  const float* embed = (const float*)d_in[1];
  const float* W1    = (const float*)d_in[2];
  const float* b1    = (const float*)d_in[3];
  const float* W2    = (const float*)d_in[4];
  const float* b2    = (const float*)d_in[5];
  const float* ln_g  = (const float*)d_in[6];
  const float* ln_b  = (const float*)d_in[7];
  const float* Wk    = (const float*)d_in[8];
  const float* Wv    = (const float*)d_in[9];
  const float* Wq    = (const float*)d_in[10];
  const float* Wr    = (const float*)d_in[11];
  const float* alpha = (const float*)d_in[12];
  const float* Wout  = (const float*)d_in[13];
  const float* bout  = (const float*)d_in[14];
  float* out = (float*)d_out;

  const int B = in_sizes[0] / LSEQ;

  float* ws    = (float*)d_ws;
  float* Htab  = ws;          // 4096
  float* Ktab  = ws + 4096;   // 4096
  float* Vtab  = ws + 8192;   // 4096
  float* nvtab = ws + 12288;  // 64

  tables_kernel<<<VOCABN, 64, 0, stream>>>(embed, W1, b1, W2, b2, ln_g, ln_b,
                                           Wk, Wv, Htab, Ktab, Vtab, nvtab);
  scan_kernel<<<B, 256, 0, stream>>>(x, Htab, Ktab, Vtab, nvtab,
                                     Wq, Wr, alpha, Wout, bout, out);
}